// Round 6
// baseline (412.881 us; speedup 1.0000x reference)
//
#include <hip/hip_runtime.h>

typedef float    f32x4 __attribute__((ext_vector_type(4)));
typedef short    s16x8 __attribute__((ext_vector_type(8)));
typedef unsigned u32x2 __attribute__((ext_vector_type(2)));
typedef unsigned u32x4 __attribute__((ext_vector_type(4)));

#define ND   64
#define DE   32
#define KN   128
#define KNP  136
#define K2P  72
#define WBP  40

__device__ __forceinline__ ushort f2bf(float f) {
  unsigned u = __float_as_uint(f);
  return (ushort)((u + 0x7fffu + ((u >> 16) & 1u)) >> 16);  // RNE
}
__device__ __forceinline__ float relu_f(float v) { return v > 0.f ? v : 0.f; }
__device__ __forceinline__ unsigned cvtpk(float lo, float hi) {
  unsigned r;
  asm("v_cvt_pk_bf16_f32 %0, %1, %2" : "=v"(r) : "v"(lo), "v"(hi));
  return r;
}
__device__ __forceinline__ float bflo(unsigned u) { return __uint_as_float(u << 16); }
__device__ __forceinline__ float bfhi(unsigned u) { return __uint_as_float(u & 0xffff0000u); }

// ---- P/Q precompute: P = x@W1e[0:64], Q = x@W1e[64:128], stored bf16 -------
__launch_bounds__(256, 2)
__global__ void gc_pq(const float* __restrict__ x,
                      const float* __restrict__ W1e,
                      unsigned* __restrict__ PQ,   // [N][64] dwords: P dw0..31, Q dw32..63
                      int N) {
  __shared__ ushort xl[64][K2P];
  __shared__ ushort wtA[ND][K2P];
  __shared__ ushort wtB[ND][K2P];

  const int t = threadIdx.x, lane = t & 63, w = t >> 6;
  const int l15 = lane & 15, lhi = lane >> 4, k8 = lhi * 8;

  for (int i = t; i < ND * ND; i += 256) {
    wtA[i & 63][i >> 6] = f2bf(W1e[i]);                       // k = i>>6 (0..63)
    wtB[i & 63][i >> 6] = f2bf(W1e[(size_t)ND * ND + i]);     // k = 64..127
  }
  const int n0 = blockIdx.x * 64;
  #pragma unroll
  for (int i = 0; i < 4; ++i) {
    int chunk = t + i * 256;
    int r = chunk >> 4, p = chunk & 15;
    int node = n0 + r; if (node >= N) node = N - 1;
    f32x4 v = *(const f32x4*)(x + (size_t)node * ND + p * 4);
    unsigned* dst = (unsigned*)&xl[r][p * 4];
    dst[0] = cvtpk(v.x, v.y); dst[1] = cvtpk(v.z, v.w);
  }
  __syncthreads();

  const int strip = w * 16;
  const int ar = strip + l15;
  s16x8 a0 = *(const s16x8*)&xl[ar][k8];
  s16x8 a1 = *(const s16x8*)&xl[ar][32 + k8];

  f32x4 accP[4] = {}, accQ[4] = {};
  #pragma unroll
  for (int n = 0; n < 4; ++n) {
    s16x8 bA0 = *(const s16x8*)&wtA[n * 16 + l15][k8];
    s16x8 bA1 = *(const s16x8*)&wtA[n * 16 + l15][32 + k8];
    s16x8 bB0 = *(const s16x8*)&wtB[n * 16 + l15][k8];
    s16x8 bB1 = *(const s16x8*)&wtB[n * 16 + l15][32 + k8];
    accP[n] = __builtin_amdgcn_mfma_f32_16x16x32_bf16(a0, bA0, accP[n], 0, 0, 0);
    accP[n] = __builtin_amdgcn_mfma_f32_16x16x32_bf16(a1, bA1, accP[n], 0, 0, 0);
    accQ[n] = __builtin_amdgcn_mfma_f32_16x16x32_bf16(a0, bB0, accQ[n], 0, 0, 0);
    accQ[n] = __builtin_amdgcn_mfma_f32_16x16x32_bf16(a1, bB1, accQ[n], 0, 0, 0);
  }
  #pragma unroll
  for (int n = 0; n < 4; ++n) {
    #pragma unroll
    for (int j = 0; j < 4; ++j) {
      int node = n0 + strip + lhi * 4 + j;
      float rP = accP[n][j];  float pP = __shfl_xor(rP, 1);
      float rQ = accQ[n][j];  float pQ = __shfl_xor(rQ, 1);
      if (!(l15 & 1) && node < N) {
        unsigned dw = (unsigned)(n * 16 + l15) >> 1;
        PQ[(size_t)node * 64 + dw]      = cvtpk(rP, pP);
        PQ[(size_t)node * 64 + 32 + dw] = cvtpk(rQ, pQ);
      }
    }
  }
}

// ---- edge kernel: h = ReLU(P[row]+Q[col]+attr@W1bot+b1e) -> pk_bf16 scatter
__launch_bounds__(256, 4)
__global__ void gc_edge_pq(const int* __restrict__ eidx,     // [2][E]
                           const float* __restrict__ eattr,  // [E][32]
                           const float* __restrict__ W1e, const float* __restrict__ b1e,
                           const unsigned* __restrict__ PQ,  // [N][64] dwords bf16
                           unsigned* __restrict__ hsum,      // [N][32] dwords bf16
                           float* __restrict__ deg,
                           int E, int ngroups) {
  __shared__ ushort   w1bt[ND][WBP];     // W1e rows 128..159 transposed
  __shared__ unsigned hb[4][16][32];     // per-wave R+bias rows (bf16 pairs)

  const int t = threadIdx.x, lane = t & 63, w = t >> 6;
  const int l15 = lane & 15, lhi = lane >> 4, k8 = lhi * 8;

  for (int i = t; i < DE * ND; i += 256)
    w1bt[i & 63][i >> 6] = f2bf(W1e[(size_t)KN * ND + i]);   // k = 128 + (i>>6)
  __syncthreads();

  s16x8 bfr[4];
  #pragma unroll
  for (int n = 0; n < 4; ++n) bfr[n] = *(const s16x8*)&w1bt[n * 16 + l15][k8];

  float bias[4];
  #pragma unroll
  for (int n = 0; n < 4; ++n) bias[n] = b1e[n * 16 + l15];

  const int e8   = lane >> 3;   // 0..7: edge (batch-local) for P/Q/combine
  const int part = lane & 7;    // 16B slot within 128B row

  const int wid = blockIdx.x * 4 + w;
  const int nw  = gridDim.x * 4;

  for (int g = wid; g < ngroups; g += nw) {
    const int e0 = g * 16;
    int myidx = 0;
    if (lane < 32)
      myidx = (lane < 16) ? eidx[e0 + lane] : eidx[E + e0 + (lane - 16)];

    const int r0 = __shfl(myidx, e8);
    const int r1 = __shfl(myidx, 8 + e8);
    const int c0 = __shfl(myidx, 16 + e8);
    const int c1 = __shfl(myidx, 24 + e8);

    // gather P rows / Q rows (bf16, 16B per lane, 8 edges per instr)
    u32x4 P0 = *(const u32x4*)(PQ + (size_t)r0 * 64 + part * 4);
    u32x4 P1 = *(const u32x4*)(PQ + (size_t)r1 * 64 + part * 4);
    u32x4 Q0 = *(const u32x4*)(PQ + (size_t)c0 * 64 + 32 + part * 4);
    u32x4 Q1 = *(const u32x4*)(PQ + (size_t)c1 * 64 + 32 + part * 4);

    // eattr straight into A-fragment layout (nontemporal, coalesced 2KB/iter)
    const float* ap = eattr + ((size_t)e0 + l15) * DE + k8;
    f32x4 alo = __builtin_nontemporal_load((const f32x4*)ap);
    f32x4 ahi = __builtin_nontemporal_load((const f32x4*)(ap + 4));
    union { unsigned u[4]; s16x8 v; } af;
    af.u[0] = cvtpk(alo.x, alo.y); af.u[1] = cvtpk(alo.z, alo.w);
    af.u[2] = cvtpk(ahi.x, ahi.y); af.u[3] = cvtpk(ahi.z, ahi.w);

    f32x4 acc[4] = {};
    #pragma unroll
    for (int n = 0; n < 4; ++n)
      acc[n] = __builtin_amdgcn_mfma_f32_16x16x32_bf16(af.v, bfr[n], acc[n], 0, 0, 0);

    if (lane >= 16 && lane < 32) atomicAdd(&deg[myidx], 1.0f);

    // pack R+bias (no ReLU yet) into hb, transposing MFMA C-layout -> row layout
    #pragma unroll
    for (int n = 0; n < 4; ++n) {
      #pragma unroll
      for (int j = 0; j < 4; ++j) {
        float r = acc[n][j] + bias[n];
        float p = __shfl_xor(r, 1);
        if (!(l15 & 1)) hb[w][lhi * 4 + j][(n * 16 + l15) >> 1] = cvtpk(r, p);
      }
    }
    asm volatile("s_waitcnt lgkmcnt(0)" ::: "memory");

    u32x4 R0 = *(const u32x4*)&hb[w][e8][part * 4];
    u32x4 R1 = *(const u32x4*)&hb[w][8 + e8][part * 4];

    unsigned* h0 = hsum + (size_t)c0 * 32 + part * 4;
    unsigned* h1 = hsum + (size_t)c1 * 32 + part * 4;
    #pragma unroll
    for (int k = 0; k < 4; ++k) {
      float slo = relu_f(bflo(P0[k]) + bflo(Q0[k]) + bflo(R0[k]));
      float shi = relu_f(bfhi(P0[k]) + bfhi(Q0[k]) + bfhi(R0[k]));
      unsigned dw = cvtpk(slo, shi);
      asm volatile("global_atomic_pk_add_bf16 %0, %1, off"
                   :: "v"((uint64_t)(h0 + k)), "v"(dw) : "memory");
    }
    #pragma unroll
    for (int k = 0; k < 4; ++k) {
      float slo = relu_f(bflo(P1[k]) + bflo(Q1[k]) + bflo(R1[k]));
      float shi = relu_f(bfhi(P1[k]) + bfhi(Q1[k]) + bfhi(R1[k]));
      unsigned dw = cvtpk(slo, shi);
      asm volatile("global_atomic_pk_add_bf16 %0, %1, off"
                   :: "v"((uint64_t)(h1 + k)), "v"(dw) : "memory");
    }
  }
}

// ---- node kernel: agg = hsum@W2e + deg*b2e; node MLP + residual ------------
__launch_bounds__(256, 2)
__global__ void gc_node(const float* __restrict__ x,
                        const ushort* __restrict__ hsum,
                        const float* __restrict__ deg,
                        const float* __restrict__ W2e, const float* __restrict__ b2e,
                        const float* __restrict__ W1n, const float* __restrict__ b1n,
                        const float* __restrict__ W2n, const float* __restrict__ b2n,
                        float* __restrict__ out, int N) {
  __shared__ ushort w2et[ND][K2P];
  __shared__ ushort w1nt[ND][KNP];
  __shared__ ushort w2nt[ND][K2P];
  __shared__ ushort in_lds[64][KNP];
  __shared__ ushort h_lds[64][K2P];

  const int t    = threadIdx.x;
  const int lane = t & 63;
  const int w    = t >> 6;
  const int l15  = lane & 15;
  const int lhi  = lane >> 4;
  const int k8   = lhi * 8;

  for (int i = t; i < 64 * ND; i += 256) w2et[i & 63][i >> 6] = f2bf(W2e[i]);
  for (int i = t; i < KN * ND; i += 256) w1nt[i & 63][i >> 6] = f2bf(W1n[i]);
  for (int i = t; i < 64 * ND; i += 256) w2nt[i & 63][i >> 6] = f2bf(W2n[i]);

  const int n0 = blockIdx.x * 64;
  #pragma unroll
  for (int i = 0; i < 4; ++i) {
    int chunk = t + i * 256;
    int r = chunk >> 4, p = chunk & 15;
    int node = n0 + r; if (node >= N) node = N - 1;
    f32x4 v = *(const f32x4*)(x + (size_t)node * ND + p * 4);
    unsigned* dst = (unsigned*)&in_lds[r][p * 4];
    dst[0] = cvtpk(v.x, v.y); dst[1] = cvtpk(v.z, v.w);
  }

  const int strip = w * 16;
  {
    int arow = strip + l15;
    int node = n0 + arow; if (node >= N) node = N - 1;
    const s16x8* ph = (const s16x8*)(hsum + (size_t)node * ND);
    s16x8 a0 = ph[lhi];
    s16x8 a1 = ph[4 + lhi];
    __syncthreads();
    f32x4 accg[4] = {};
    #pragma unroll
    for (int n = 0; n < 4; ++n) {
      s16x8 b0 = *(const s16x8*)&w2et[n * 16 + l15][k8];
      s16x8 b1 = *(const s16x8*)&w2et[n * 16 + l15][32 + k8];
      accg[n] = __builtin_amdgcn_mfma_f32_16x16x32_bf16(a0, b0, accg[n], 0, 0, 0);
      accg[n] = __builtin_amdgcn_mfma_f32_16x16x32_bf16(a1, b1, accg[n], 0, 0, 0);
    }
    #pragma unroll
    for (int n = 0; n < 4; ++n) {
      int d = n * 16 + l15;
      float b2 = b2e[d];
      #pragma unroll
      for (int j = 0; j < 4; ++j) {
        int r = strip + lhi * 4 + j;
        int node2 = n0 + r; if (node2 >= N) node2 = N - 1;
        float ag = accg[n][j] + deg[node2] * b2;
        in_lds[r][64 + d] = f2bf(ag);
      }
    }
  }
  __syncthreads();

  const int ar = strip + l15;
  f32x4 acc1[4] = {};
  #pragma unroll
  for (int ks = 0; ks < 4; ++ks) {
    s16x8 a = *(const s16x8*)&in_lds[ar][ks * 32 + k8];
    #pragma unroll
    for (int n = 0; n < 4; ++n) {
      s16x8 b = *(const s16x8*)&w1nt[n * 16 + l15][ks * 32 + k8];
      acc1[n] = __builtin_amdgcn_mfma_f32_16x16x32_bf16(a, b, acc1[n], 0, 0, 0);
    }
  }
  #pragma unroll
  for (int n = 0; n < 4; ++n) {
    int d = n * 16 + l15;
    float bias = b1n[d];
    #pragma unroll
    for (int j = 0; j < 4; ++j)
      h_lds[strip + lhi * 4 + j][d] = f2bf(relu_f(acc1[n][j] + bias));
  }
  __syncthreads();

  f32x4 acc2[4] = {};
  #pragma unroll
  for (int ks = 0; ks < 2; ++ks) {
    s16x8 a = *(const s16x8*)&h_lds[ar][ks * 32 + k8];
    #pragma unroll
    for (int n = 0; n < 4; ++n) {
      s16x8 b = *(const s16x8*)&w2nt[n * 16 + l15][ks * 32 + k8];
      acc2[n] = __builtin_amdgcn_mfma_f32_16x16x32_bf16(a, b, acc2[n], 0, 0, 0);
    }
  }
  #pragma unroll
  for (int n = 0; n < 4; ++n) {
    int d = n * 16 + l15;
    float bias = b2n[d];
    #pragma unroll
    for (int j = 0; j < 4; ++j) {
      int node = n0 + strip + lhi * 4 + j;
      if (node < N) {
        float xv = x[(size_t)node * ND + d];
        out[(size_t)node * ND + d] = relu_f(acc2[n][j] + bias + xv);
      }
    }
  }
}

extern "C" void kernel_launch(void* const* d_in, const int* in_sizes, int n_in,
                              void* d_out, int out_size, void* d_ws, size_t ws_size,
                              hipStream_t stream) {
  const float* x     = (const float*)d_in[0];
  const int*   eidx  = (const int*)d_in[1];
  const float* eattr = (const float*)d_in[2];
  const float* W1e   = (const float*)d_in[3];
  const float* b1e   = (const float*)d_in[4];
  const float* W2e   = (const float*)d_in[5];
  const float* b2e   = (const float*)d_in[6];
  const float* W1n   = (const float*)d_in[7];
  const float* b1n   = (const float*)d_in[8];
  const float* W2n   = (const float*)d_in[9];
  const float* b2n   = (const float*)d_in[10];
  float* out = (float*)d_out;

  const int N = in_sizes[0] / ND;   // 50000
  const int E = in_sizes[1] / 2;    // 800000

  // ws layout: hsum [N][64] bf16 | deg [N] f32 | PQ [N][64] dwords
  char* ws = (char*)d_ws;
  unsigned* hsum = (unsigned*)ws;                              // N*32 dwords
  float*    deg  = (float*)(ws + (size_t)N * ND * 2);          // N f32
  unsigned* PQ   = (unsigned*)(ws + (size_t)N * ND * 2 + (size_t)N * 4);

  hipMemsetAsync(ws, 0, (size_t)N * ND * 2 + (size_t)N * 4, stream);

  gc_pq<<<(N + 63) / 64, 256, 0, stream>>>(x, W1e, PQ, N);
  gc_edge_pq<<<2048, 256, 0, stream>>>(eidx, eattr, W1e, b1e, PQ,
                                       hsum, deg, E, E / 16);
  gc_node<<<(N + 63) / 64, 256, 0, stream>>>(x, (const ushort*)hsum, deg,
                                             W2e, b2e, W1n, b1n, W2n, b2n, out, N);
}

// Round 7
// 173.920 us; speedup vs baseline: 2.3740x; 2.3740x over previous
//
#include <hip/hip_runtime.h>

typedef float    f32x4 __attribute__((ext_vector_type(4)));
typedef short    s16x8 __attribute__((ext_vector_type(8)));
typedef unsigned u32x2 __attribute__((ext_vector_type(2)));
typedef unsigned u32x4 __attribute__((ext_vector_type(4)));

#define ND   64
#define DE   32
#define KN   128
#define KNP  136
#define K2P  72
#define WBP  40

__device__ __forceinline__ ushort f2bf(float f) {
  unsigned u = __float_as_uint(f);
  return (ushort)((u + 0x7fffu + ((u >> 16) & 1u)) >> 16);  // RNE
}
__device__ __forceinline__ float relu_f(float v) { return v > 0.f ? v : 0.f; }
__device__ __forceinline__ unsigned cvtpk(float lo, float hi) {
  unsigned r;
  asm("v_cvt_pk_bf16_f32 %0, %1, %2" : "=v"(r) : "v"(lo), "v"(hi));
  return r;
}
__device__ __forceinline__ float bflo(unsigned u) { return __uint_as_float(u << 16); }
__device__ __forceinline__ float bfhi(unsigned u) { return __uint_as_float(u & 0xffff0000u); }

// ---- P/Q precompute: P = x@W1e[0:64], Q = x@W1e[64:128], stored bf16 -------
__launch_bounds__(256, 2)
__global__ void gc_pq(const float* __restrict__ x,
                      const float* __restrict__ W1e,
                      unsigned* __restrict__ PQ,   // [N][64] dwords: P dw0..31, Q dw32..63
                      int N) {
  __shared__ ushort xl[64][K2P];
  __shared__ ushort wtA[ND][K2P];
  __shared__ ushort wtB[ND][K2P];

  const int t = threadIdx.x, lane = t & 63, w = t >> 6;
  const int l15 = lane & 15, lhi = lane >> 4, k8 = lhi * 8;

  for (int i = t; i < ND * ND; i += 256) {
    wtA[i & 63][i >> 6] = f2bf(W1e[i]);
    wtB[i & 63][i >> 6] = f2bf(W1e[(size_t)ND * ND + i]);
  }
  const int n0 = blockIdx.x * 64;
  #pragma unroll
  for (int i = 0; i < 4; ++i) {
    int chunk = t + i * 256;
    int r = chunk >> 4, p = chunk & 15;
    int node = n0 + r; if (node >= N) node = N - 1;
    f32x4 v = *(const f32x4*)(x + (size_t)node * ND + p * 4);
    unsigned* dst = (unsigned*)&xl[r][p * 4];
    dst[0] = cvtpk(v.x, v.y); dst[1] = cvtpk(v.z, v.w);
  }
  __syncthreads();

  const int strip = w * 16;
  const int ar = strip + l15;
  s16x8 a0 = *(const s16x8*)&xl[ar][k8];
  s16x8 a1 = *(const s16x8*)&xl[ar][32 + k8];

  f32x4 accP[4] = {}, accQ[4] = {};
  #pragma unroll
  for (int n = 0; n < 4; ++n) {
    s16x8 bA0 = *(const s16x8*)&wtA[n * 16 + l15][k8];
    s16x8 bA1 = *(const s16x8*)&wtA[n * 16 + l15][32 + k8];
    s16x8 bB0 = *(const s16x8*)&wtB[n * 16 + l15][k8];
    s16x8 bB1 = *(const s16x8*)&wtB[n * 16 + l15][32 + k8];
    accP[n] = __builtin_amdgcn_mfma_f32_16x16x32_bf16(a0, bA0, accP[n], 0, 0, 0);
    accP[n] = __builtin_amdgcn_mfma_f32_16x16x32_bf16(a1, bA1, accP[n], 0, 0, 0);
    accQ[n] = __builtin_amdgcn_mfma_f32_16x16x32_bf16(a0, bB0, accQ[n], 0, 0, 0);
    accQ[n] = __builtin_amdgcn_mfma_f32_16x16x32_bf16(a1, bB1, accQ[n], 0, 0, 0);
  }
  #pragma unroll
  for (int n = 0; n < 4; ++n) {
    #pragma unroll
    for (int j = 0; j < 4; ++j) {
      int node = n0 + strip + lhi * 4 + j;
      float rP = accP[n][j];  float pP = __shfl_xor(rP, 1);
      float rQ = accQ[n][j];  float pQ = __shfl_xor(rQ, 1);
      if (!(l15 & 1) && node < N) {
        unsigned dw = (unsigned)(n * 16 + l15) >> 1;
        PQ[(size_t)node * 64 + dw]      = cvtpk(rP, pP);
        PQ[(size_t)node * 64 + 32 + dw] = cvtpk(rQ, pQ);
      }
    }
  }
}

// ---- edge kernel: h = ReLU(P[row]+Q[col]+attr@W1bot+b1e) -> pk_bf16 scatter
// Gathers AND scatters in 4-rows x 64B-line shape (the R3-proven transaction form).
__launch_bounds__(256, 4)
__global__ void gc_edge_pq(const int* __restrict__ eidx,     // [2][E]
                           const float* __restrict__ eattr,  // [E][32]
                           const float* __restrict__ W1e, const float* __restrict__ b1e,
                           const unsigned* __restrict__ PQ,  // [N][64] dwords bf16
                           unsigned* __restrict__ hsum,      // [N][32] dwords bf16
                           float* __restrict__ deg,
                           int E, int ngroups) {
  __shared__ ushort   w1bt[ND][WBP];     // W1e rows 128..159 transposed
  __shared__ unsigned hb[4][16][33];     // per-wave R+bias rows (bf16 pairs)

  const int t = threadIdx.x, lane = t & 63, w = t >> 6;
  const int l15 = lane & 15, lhi = lane >> 4, k8 = lhi * 8;

  for (int i = t; i < DE * ND; i += 256)
    w1bt[i & 63][i >> 6] = f2bf(W1e[(size_t)KN * ND + i]);   // k = 128 + (i>>6)
  __syncthreads();

  s16x8 bfr[4];
  #pragma unroll
  for (int n = 0; n < 4; ++n) bfr[n] = *(const s16x8*)&w1bt[n * 16 + l15][k8];

  float bias[4];
  #pragma unroll
  for (int n = 0; n < 4; ++n) bias[n] = b1e[n * 16 + l15];

  const int ee4 = lhi;      // row-within-4 for gather/scatter shape
  const int q16 = l15;      // dword-within-64B

  const int wid = blockIdx.x * 4 + w;
  const int nw  = gridDim.x * 4;

  for (int g = wid; g < ngroups; g += nw) {
    const int e0 = g * 16;
    int myidx = 0;
    if (lane < 32)
      myidx = (lane < 16) ? eidx[e0 + lane] : eidx[E + e0 + (lane - 16)];

    int prow[4], pcol[4];
    #pragma unroll
    for (int m = 0; m < 4; ++m) {
      prow[m] = __shfl(myidx, m * 4 + ee4);
      pcol[m] = __shfl(myidx, 16 + m * 4 + ee4);
    }

    // P[row], Q[col] gathers: each instr = 4 rows x 64B contiguous
    unsigned Pv[4][2], Qv[4][2];
    #pragma unroll
    for (int m = 0; m < 4; ++m) {
      const unsigned* pb = PQ + (size_t)prow[m] * 64;
      const unsigned* qb = PQ + (size_t)pcol[m] * 64 + 32;
      Pv[m][0] = pb[q16];      Pv[m][1] = pb[16 + q16];
      Qv[m][0] = qb[q16];      Qv[m][1] = qb[16 + q16];
    }

    // eattr straight into A-fragment layout (nontemporal, coalesced 2KB/iter)
    const float* ap = eattr + ((size_t)e0 + l15) * DE + k8;
    f32x4 alo = __builtin_nontemporal_load((const f32x4*)ap);
    f32x4 ahi = __builtin_nontemporal_load((const f32x4*)(ap + 4));
    union { unsigned u[4]; s16x8 v; } af;
    af.u[0] = cvtpk(alo.x, alo.y); af.u[1] = cvtpk(alo.z, alo.w);
    af.u[2] = cvtpk(ahi.x, ahi.y); af.u[3] = cvtpk(ahi.z, ahi.w);

    f32x4 acc[4] = {};
    #pragma unroll
    for (int n = 0; n < 4; ++n)
      acc[n] = __builtin_amdgcn_mfma_f32_16x16x32_bf16(af.v, bfr[n], acc[n], 0, 0, 0);

    if (lane >= 16 && lane < 32) atomicAdd(&deg[myidx], 1.0f);

    // pack R = acc + bias into hb (row layout, bf16 pairs), wave-private
    #pragma unroll
    for (int n = 0; n < 4; ++n) {
      #pragma unroll
      for (int j = 0; j < 4; ++j) {
        float r = acc[n][j] + bias[n];
        float p = __shfl_xor(r, 1);
        if (!(l15 & 1)) hb[w][lhi * 4 + j][(n * 16 + l15) >> 1] = cvtpk(r, p);
      }
    }
    asm volatile("s_waitcnt lgkmcnt(0)" ::: "memory");

    // combine + scatter: each atomic instr = 4 rows x 16 contiguous dwords (64B/row)
    #pragma unroll
    for (int m = 0; m < 4; ++m) {
      unsigned* hd = hsum + (size_t)pcol[m] * 32 + q16;
      #pragma unroll
      for (int h = 0; h < 2; ++h) {
        unsigned R  = hb[w][m * 4 + ee4][h * 16 + q16];
        unsigned Pu = Pv[m][h], Qu = Qv[m][h];
        float slo = relu_f(bflo(Pu) + bflo(Qu) + bflo(R));
        float shi = relu_f(bfhi(Pu) + bfhi(Qu) + bfhi(R));
        unsigned dw = cvtpk(slo, shi);
        asm volatile("global_atomic_pk_add_bf16 %0, %1, off"
                     :: "v"((uint64_t)(hd + h * 16)), "v"(dw) : "memory");
      }
    }
  }
}

// ---- node kernel: agg = hsum@W2e + deg*b2e; node MLP + residual ------------
__launch_bounds__(256, 2)
__global__ void gc_node(const float* __restrict__ x,
                        const ushort* __restrict__ hsum,
                        const float* __restrict__ deg,
                        const float* __restrict__ W2e, const float* __restrict__ b2e,
                        const float* __restrict__ W1n, const float* __restrict__ b1n,
                        const float* __restrict__ W2n, const float* __restrict__ b2n,
                        float* __restrict__ out, int N) {
  __shared__ ushort w2et[ND][K2P];
  __shared__ ushort w1nt[ND][KNP];
  __shared__ ushort w2nt[ND][K2P];
  __shared__ ushort in_lds[64][KNP];
  __shared__ ushort h_lds[64][K2P];

  const int t    = threadIdx.x;
  const int lane = t & 63;
  const int w    = t >> 6;
  const int l15  = lane & 15;
  const int lhi  = lane >> 4;
  const int k8   = lhi * 8;

  for (int i = t; i < 64 * ND; i += 256) w2et[i & 63][i >> 6] = f2bf(W2e[i]);
  for (int i = t; i < KN * ND; i += 256) w1nt[i & 63][i >> 6] = f2bf(W1n[i]);
  for (int i = t; i < 64 * ND; i += 256) w2nt[i & 63][i >> 6] = f2bf(W2n[i]);

  const int n0 = blockIdx.x * 64;
  #pragma unroll
  for (int i = 0; i < 4; ++i) {
    int chunk = t + i * 256;
    int r = chunk >> 4, p = chunk & 15;
    int node = n0 + r; if (node >= N) node = N - 1;
    f32x4 v = *(const f32x4*)(x + (size_t)node * ND + p * 4);
    unsigned* dst = (unsigned*)&in_lds[r][p * 4];
    dst[0] = cvtpk(v.x, v.y); dst[1] = cvtpk(v.z, v.w);
  }

  const int strip = w * 16;
  {
    int arow = strip + l15;
    int node = n0 + arow; if (node >= N) node = N - 1;
    const s16x8* ph = (const s16x8*)(hsum + (size_t)node * ND);
    s16x8 a0 = ph[lhi];
    s16x8 a1 = ph[4 + lhi];
    __syncthreads();
    f32x4 accg[4] = {};
    #pragma unroll
    for (int n = 0; n < 4; ++n) {
      s16x8 b0 = *(const s16x8*)&w2et[n * 16 + l15][k8];
      s16x8 b1 = *(const s16x8*)&w2et[n * 16 + l15][32 + k8];
      accg[n] = __builtin_amdgcn_mfma_f32_16x16x32_bf16(a0, b0, accg[n], 0, 0, 0);
      accg[n] = __builtin_amdgcn_mfma_f32_16x16x32_bf16(a1, b1, accg[n], 0, 0, 0);
    }
    #pragma unroll
    for (int n = 0; n < 4; ++n) {
      int d = n * 16 + l15;
      float b2 = b2e[d];
      #pragma unroll
      for (int j = 0; j < 4; ++j) {
        int r = strip + lhi * 4 + j;
        int node2 = n0 + r; if (node2 >= N) node2 = N - 1;
        float ag = accg[n][j] + deg[node2] * b2;
        in_lds[r][64 + d] = f2bf(ag);
      }
    }
  }
  __syncthreads();

  const int ar = strip + l15;
  f32x4 acc1[4] = {};
  #pragma unroll
  for (int ks = 0; ks < 4; ++ks) {
    s16x8 a = *(const s16x8*)&in_lds[ar][ks * 32 + k8];
    #pragma unroll
    for (int n = 0; n < 4; ++n) {
      s16x8 b = *(const s16x8*)&w1nt[n * 16 + l15][ks * 32 + k8];
      acc1[n] = __builtin_amdgcn_mfma_f32_16x16x32_bf16(a, b, acc1[n], 0, 0, 0);
    }
  }
  #pragma unroll
  for (int n = 0; n < 4; ++n) {
    int d = n * 16 + l15;
    float bias = b1n[d];
    #pragma unroll
    for (int j = 0; j < 4; ++j)
      h_lds[strip + lhi * 4 + j][d] = f2bf(relu_f(acc1[n][j] + bias));
  }
  __syncthreads();

  f32x4 acc2[4] = {};
  #pragma unroll
  for (int ks = 0; ks < 2; ++ks) {
    s16x8 a = *(const s16x8*)&h_lds[ar][ks * 32 + k8];
    #pragma unroll
    for (int n = 0; n < 4; ++n) {
      s16x8 b = *(const s16x8*)&w2nt[n * 16 + l15][ks * 32 + k8];
      acc2[n] = __builtin_amdgcn_mfma_f32_16x16x32_bf16(a, b, acc2[n], 0, 0, 0);
    }
  }
  #pragma unroll
  for (int n = 0; n < 4; ++n) {
    int d = n * 16 + l15;
    float bias = b2n[d];
    #pragma unroll
    for (int j = 0; j < 4; ++j) {
      int node = n0 + strip + lhi * 4 + j;
      if (node < N) {
        float xv = x[(size_t)node * ND + d];
        out[(size_t)node * ND + d] = relu_f(acc2[n][j] + bias + xv);
      }
    }
  }
}

extern "C" void kernel_launch(void* const* d_in, const int* in_sizes, int n_in,
                              void* d_out, int out_size, void* d_ws, size_t ws_size,
                              hipStream_t stream) {
  const float* x     = (const float*)d_in[0];
  const int*   eidx  = (const int*)d_in[1];
  const float* eattr = (const float*)d_in[2];
  const float* W1e   = (const float*)d_in[3];
  const float* b1e   = (const float*)d_in[4];
  const float* W2e   = (const float*)d_in[5];
  const float* b2e   = (const float*)d_in[6];
  const float* W1n   = (const float*)d_in[7];
  const float* b1n   = (const float*)d_in[8];
  const float* W2n   = (const float*)d_in[9];
  const float* b2n   = (const float*)d_in[10];
  float* out = (float*)d_out;

  const int N = in_sizes[0] / ND;   // 50000
  const int E = in_sizes[1] / 2;    // 800000

  // ws layout: hsum [N][64] bf16 | deg [N] f32 | PQ [N][64] dwords
  char* ws = (char*)d_ws;
  unsigned* hsum = (unsigned*)ws;                              // N*32 dwords
  float*    deg  = (float*)(ws + (size_t)N * ND * 2);          // N f32
  unsigned* PQ   = (unsigned*)(ws + (size_t)N * ND * 2 + (size_t)N * 4);

  hipMemsetAsync(ws, 0, (size_t)N * ND * 2 + (size_t)N * 4, stream);

  gc_pq<<<(N + 63) / 64, 256, 0, stream>>>(x, W1e, PQ, N);
  gc_edge_pq<<<2048, 256, 0, stream>>>(eidx, eattr, W1e, b1e, PQ,
                                       hsum, deg, E, E / 16);
  gc_node<<<(N + 63) / 64, 256, 0, stream>>>(x, (const ushort*)hsum, deg,
                                             W2e, b2e, W1n, b1n, W2n, b2n, out, N);
}